// Round 5
// baseline (269.041 us; speedup 1.0000x reference)
//
#include <hip/hip_runtime.h>
#include <cstdint>

typedef unsigned short u16;
typedef __bf16 bf16x8 __attribute__((ext_vector_type(8)));
typedef float f32x4 __attribute__((ext_vector_type(4)));
typedef u16 u16x8 __attribute__((ext_vector_type(8)));

// Problem sizes (fixed by the reference): B=8, S=2048, I=256, H=256, M=1024
#define NX 4194304L   // x / key elems  (8*2048*256)
#define NW 65536L     // W elems  (256*256)
#define NM 2097152L   // mem elems (8*1024*256)
// ws layout (u16 elems): [W_bf 0..NW) [mem_bf ..+NM) [key_bf ..+NX)
#define WS_MEM (NW)
#define WS_KEY (NW + NM)

// ---- INSTRUMENTATION ROUND (round-2 structure + internal idempotent repeats) ----
// Repeats push each kernel's dispatch above the 52us harness fills so all three
// appear in rocprof top-5 with full counters. dispatch_dur/REPS = true kernel time.
#define REPS_CONV 25
#define REPS_G1   10
#define REPS_G2   5

__device__ __forceinline__ u16 f2bf_rne(float f) {
  union { float f; uint32_t u; } v; v.f = f;
  uint32_t r = v.u + 0x7fffu + ((v.u >> 16) & 1u);
  return (u16)(r >> 16);
}

__device__ __forceinline__ u16x8 cvt8(float4 a, float4 b) {
  u16x8 o;
  o[0]=f2bf_rne(a.x); o[1]=f2bf_rne(a.y); o[2]=f2bf_rne(a.z); o[3]=f2bf_rne(a.w);
  o[4]=f2bf_rne(b.x); o[5]=f2bf_rne(b.y); o[6]=f2bf_rne(b.z); o[7]=f2bf_rne(b.w);
  return o;
}

// ---- Kernel 0: fp32 -> bf16 pre-convert of W and mem (x is fused into GEMM1) ----
__global__ void convert_bf16_kernel(const float* __restrict__ mem,
                                    const float* __restrict__ W,
                                    u16* __restrict__ ws) {
  long e = ((long)blockIdx.x * blockDim.x + threadIdx.x) * 8;
  if (e < NW + NM) {
    for (int rep = 0; rep < REPS_CONV; ++rep) {
      const float* src; long l;
      if (e < NW) { src = W;   l = e; }
      else        { src = mem; l = e - NW; }
      float4 f0 = *(const float4*)(src + l);
      float4 f1 = *(const float4*)(src + l + 4);
      *(u16x8*)(ws + e) = cvt8(f0, f1);
      asm volatile("" ::: "memory");   // keep loads+stores inside the rep loop
    }
  }
}

// ---- NT GEMM with prefetch double-buffer (round-2 best: 35.2us/pass) ----
// 128x128 tile, BK=32, 256 threads (2x2 waves of 64x64), 16x16x32 bf16 MFMA.
// bf16 operands staged via global_load_lds; CONVERT_A reg-stages fp32 A + cvt.
#define BM 128
#define BN 128
#define BK 32

template<bool CONVERT_A, bool RELU, bool STORE_BF16, int REPS>
__global__ __launch_bounds__(256, 3)
void gemm_nt(const void* __restrict__ Ap, const u16* __restrict__ B,
             float* __restrict__ C, u16* __restrict__ Cbf,
             int M, int N, int K,
             long sA_batch, long sB_batch, long sC_batch)
{
  __shared__ __align__(16) u16 sA[2][BM * BK];   // 2 x 8 KB
  __shared__ __align__(16) u16 sB[2][BN * BK];   // 2 x 8 KB
  const int tid  = threadIdx.x;
  const int wave = tid >> 6;
  const int lane = tid & 63;
  const int quad = lane >> 4;      // 0..3
  const int r    = lane & 15;      // 0..15
  const int wm   = wave >> 1;      // wave row (0..1)
  const int wn   = wave & 1;       // wave col (0..1)

  // XCD-chunked bijective block swizzle (nwg % 8 == 0 for both grids)
  const int gx  = gridDim.x, gy = gridDim.y;
  const int nwg = gx * gy * (int)gridDim.z;
  const int id  = (int)blockIdx.x + gx * ((int)blockIdx.y + gy * (int)blockIdx.z);
  const int cpx = nwg >> 3;
  const int lid = (id & 7) * cpx + (id >> 3);
  const int bx  = lid % gx;
  const int tq  = lid / gx;
  const int by  = tq % gy;
  const int bz  = tq / gy;

  const int bm    = by * BM;
  const int bn    = bx * BN;
  const int batch = bz;

  const float* Af = CONVERT_A ? ((const float*)Ap + (long)batch * sA_batch) : nullptr;
  const char*  Ab = CONVERT_A ? nullptr : (const char*)((const u16*)Ap + (long)batch * sA_batch);
  const char*  Bb = (const char*)(B + (long)batch * sB_batch);
  const long ldr = (long)K * 2;    // bf16 row stride in bytes

  const int o0 = wave * 1024 + lane * 16;

  auto stageB = [&](int buf, int kt) {
    #pragma unroll
    for (int rr = 0; rr < 2; rr++) {
      const int o    = rr * 4096 + o0;
      const int row  = o >> 6;     // 64 B per LDS row (BK*2)
      const int colb = o & 63;
      const char* g = Bb + (long)(bn + row) * ldr + (long)kt * 2 + colb;
      char* l = (char*)&sB[buf][0] + rr * 4096 + wave * 1024;
      __builtin_amdgcn_global_load_lds((const __attribute__((address_space(1))) void*)g,
                                       (__attribute__((address_space(3))) void*)l, 16, 0, 0);
    }
  };
  auto stageA_lds = [&](int buf, int kt) {
    #pragma unroll
    for (int rr = 0; rr < 2; rr++) {
      const int o    = rr * 4096 + o0;
      const int row  = o >> 6;
      const int colb = o & 63;
      const char* g = Ab + (long)(bm + row) * ldr + (long)kt * 2 + colb;
      char* l = (char*)&sA[buf][0] + rr * 4096 + wave * 1024;
      __builtin_amdgcn_global_load_lds((const __attribute__((address_space(1))) void*)g,
                                       (__attribute__((address_space(3))) void*)l, 16, 0, 0);
    }
  };

  float4 xa[4];
  const int arow = tid >> 1;
  const int ac0  = (tid & 1) * 16;
  auto loadA_f32 = [&](int kt) {
    const float* g = Af + (long)(bm + arow) * K + kt + ac0;
    #pragma unroll
    for (int c = 0; c < 4; c++) xa[c] = *(const float4*)(g + c * 4);
  };
  auto writeA_cvt = [&](int buf) {
    u16* d = &sA[buf][arow * BK + ac0];
    *(u16x8*)d       = cvt8(xa[0], xa[1]);
    *(u16x8*)(d + 8) = cvt8(xa[2], xa[3]);
  };

  for (int rep = 0; rep < REPS; ++rep) {
    f32x4 acc[4][4];
    #pragma unroll
    for (int i = 0; i < 4; i++)
      #pragma unroll
      for (int j = 0; j < 4; j++)
        acc[i][j] = f32x4{0.f, 0.f, 0.f, 0.f};

    // prologue: stage tile 0 into buffer 0 (safe across reps: epilogue reads no LDS)
    if (CONVERT_A) { loadA_f32(0); writeA_cvt(0); }
    else           { stageA_lds(0, 0); }
    stageB(0, 0);
    __syncthreads();

    const int NT = K / BK;
    for (int t = 0; t < NT; ++t) {
      const int cur = t & 1, nxt = cur ^ 1;
      const bool pf = (t + 1 < NT);
      if (pf) {                          // issue next tile's loads first
        if (CONVERT_A) loadA_f32((t + 1) * BK);
        else           stageA_lds(nxt, (t + 1) * BK);
        stageB(nxt, (t + 1) * BK);
      }

      bf16x8 af[4], bfr[4];
      #pragma unroll
      for (int i = 0; i < 4; i++)
        af[i] = *(const bf16x8*)&sA[cur][(wm * 64 + i * 16 + r) * BK + quad * 8];
      #pragma unroll
      for (int j = 0; j < 4; j++)
        bfr[j] = *(const bf16x8*)&sB[cur][(wn * 64 + j * 16 + r) * BK + quad * 8];
      #pragma unroll
      for (int i = 0; i < 4; i++)
        #pragma unroll
        for (int j = 0; j < 4; j++)
          acc[i][j] = __builtin_amdgcn_mfma_f32_16x16x32_bf16(af[i], bfr[j], acc[i][j], 0, 0, 0);

      if (CONVERT_A && pf) writeA_cvt(nxt);   // vmcnt wait lands after the MFMAs
      __syncthreads();
    }

    // epilogue: C/D layout col=lane&15, row=quad*4+reg (verified m89/m91)
    float* Co = C + (long)batch * sC_batch;
    u16*   Bo = STORE_BF16 ? (Cbf + (long)batch * sC_batch) : nullptr;
    #pragma unroll
    for (int i = 0; i < 4; i++) {
      #pragma unroll
      for (int j = 0; j < 4; j++) {
        #pragma unroll
        for (int reg = 0; reg < 4; reg++) {
          const int row = bm + wm * 64 + i * 16 + quad * 4 + reg;
          const int col = bn + wn * 64 + j * 16 + r;
          float v = acc[i][j][reg];
          if (RELU) v = v > 0.f ? v : 0.f;
          const long idx = (long)row * N + col;
          Co[idx] = v;
          if (STORE_BF16) Bo[idx] = f2bf_rne(v);
        }
      }
    }
  }
}

extern "C" void kernel_launch(void* const* d_in, const int* in_sizes, int n_in,
                              void* d_out, int out_size, void* d_ws, size_t ws_size,
                              hipStream_t stream) {
  const float* x   = (const float*)d_in[0];  // (8,2048,256)
  const float* mem = (const float*)d_in[1];  // (8,1024,256)
  const float* W   = (const float*)d_in[2];  // (256,256)
  float* out   = (float*)d_out;
  float* key_f = out;            // (16384,256)
  float* val_f = out + NX;       // (8,2048,1024)
  u16* ws     = (u16*)d_ws;
  u16* W_bf   = ws;
  u16* mem_bf = ws + WS_MEM;
  u16* key_bf = ws + WS_KEY;

  // 0) convert W + mem to bf16 (x25 internal)
  convert_bf16_kernel<<<(int)((NW + NM) / 8 / 256), 256, 0, stream>>>(mem, W, ws);

  // 1) key = relu(x @ W^T): M=16384, N=256, K=256 (x10 internal);
  //    x converted in-kernel, dual-store fp32 + bf16
  dim3 g1(256 / BN, 16384 / BM, 1);
  gemm_nt<true, true, true, REPS_G1><<<g1, 256, 0, stream>>>(x, W_bf, key_f, key_bf,
                                                             16384, 256, 256, 0, 0, 0);

  // 2) val_b = key_b @ mem_b^T: per batch M=2048, N=1024, K=256 (x5 internal)
  dim3 g2(1024 / BN, 2048 / BM, 8);
  gemm_nt<false, false, false, REPS_G2><<<g2, 256, 0, stream>>>(key_bf, mem_bf, val_f, nullptr,
                                                                2048, 1024, 256,
                                                                (long)2048 * 256, (long)1024 * 256,
                                                                (long)2048 * 1024);
}

// Round 7
// 124.709 us; speedup vs baseline: 2.1573x; 2.1573x over previous
//
#include <hip/hip_runtime.h>
#include <cstdint>

typedef unsigned short u16;
typedef __bf16 bf16x8 __attribute__((ext_vector_type(8)));
typedef float f32x4 __attribute__((ext_vector_type(4)));
typedef u16 u16x8 __attribute__((ext_vector_type(8)));

// Problem sizes (fixed by the reference): B=8, S=2048, I=256, H=256, M=1024
#define NX 4194304L   // x / key elems  (8*2048*256)
#define NW 65536L     // W elems  (256*256)
#define NM 2097152L   // mem elems (8*1024*256)
// ws layout (u16 elems): [W_bf 0..NW) [mem_bf ..+NM) [key_bf ..+NX)
#define WS_MEM (NW)
#define WS_KEY (NW + NM)

__device__ __forceinline__ u16 f2bf_rne(float f) {
  union { float f; uint32_t u; } v; v.f = f;
  uint32_t r = v.u + 0x7fffu + ((v.u >> 16) & 1u);
  return (u16)(r >> 16);
}

__device__ __forceinline__ u16x8 cvt8(float4 a, float4 b) {
  u16x8 o;
  o[0]=f2bf_rne(a.x); o[1]=f2bf_rne(a.y); o[2]=f2bf_rne(a.z); o[3]=f2bf_rne(a.w);
  o[4]=f2bf_rne(b.x); o[5]=f2bf_rne(b.y); o[6]=f2bf_rne(b.z); o[7]=f2bf_rne(b.w);
  return o;
}

// ---- Kernel 0: fp32 -> bf16 pre-convert of W and mem (x is fused into GEMM1) ----
__global__ void convert_bf16_kernel(const float* __restrict__ mem,
                                    const float* __restrict__ W,
                                    u16* __restrict__ ws) {
  long e = ((long)blockIdx.x * blockDim.x + threadIdx.x) * 8;
  if (e >= NW + NM) return;
  const float* src; long l;
  if (e < NW) { src = W;   l = e; }
  else        { src = mem; l = e - NW; }
  float4 f0 = *(const float4*)(src + l);
  float4 f1 = *(const float4*)(src + l + 4);
  *(u16x8*)(ws + e) = cvt8(f0, f1);
}

// ================= GEMM1: key = relu(x @ W^T), dual-store fp32+bf16 ==========
// R5 counters showed GEMM1 latency-bound: grid 256 blocks = 1 block/CU =
// 1 wave/SIMD (Occupancy ~10%, MfmaUtil 7.8%, VALUBusy 13.5%, HBM 45%).
// Fix: BM 128->64 => 512 blocks = 2 blocks/CU = 2 waves/SIMD, so one block's
// MFMA overlaps the other's stage/barrier stall. Everything else unchanged.
// x (fp32) reg-staged + converted; W (bf16) via global_load_lds.
#define G1_BM 64
#define G1_BN 128
#define BK 32

__global__ __launch_bounds__(256, 2)
void gemm1_x(const float* __restrict__ x, const u16* __restrict__ Wb,
             float* __restrict__ key_f, u16* __restrict__ key_bf)
{
  const int K = 256, N = 256;
  __shared__ __align__(16) u16 sA[2][G1_BM * BK];   // 2 x 4 KB
  __shared__ __align__(16) u16 sB[2][G1_BN * BK];   // 2 x 8 KB
  const int tid  = threadIdx.x;
  const int wave = tid >> 6;
  const int lane = tid & 63;
  const int quad = lane >> 4;
  const int r    = lane & 15;
  const int wm   = wave >> 1;      // 0..1 (row half, 32 rows each)
  const int wn   = wave & 1;       // 0..1 (col half, 64 cols each)

  // XCD-chunked bijective swizzle (nwg=512, %8==0). Consecutive logical ids
  // (the two bx of one by, sharing an x-panel) land on the same XCD.
  const int gx  = gridDim.x;
  const int nwg = gx * (int)gridDim.y;
  const int id  = (int)blockIdx.x + gx * (int)blockIdx.y;
  const int cpx = nwg >> 3;
  const int lid = (id & 7) * cpx + (id >> 3);
  const int bm  = (lid / gx) * G1_BM;
  const int bn  = (lid % gx) * G1_BN;

  const long ldr = (long)K * 2;    // bf16 row stride in bytes

  f32x4 acc[2][4];
  #pragma unroll
  for (int i = 0; i < 2; i++)
    #pragma unroll
    for (int j = 0; j < 4; j++)
      acc[i][j] = f32x4{0.f, 0.f, 0.f, 0.f};

  // B staging via global_load_lds: 8 KB tile, 256 thr x 16 B x 2
  const int o0 = wave * 1024 + lane * 16;
  auto stageB = [&](int buf, int kt) {
    #pragma unroll
    for (int rr = 0; rr < 2; rr++) {
      const int o    = rr * 4096 + o0;
      const int row  = o >> 6;
      const int colb = o & 63;
      const char* g = (const char*)Wb + (long)(bn + row) * ldr + (long)kt * 2 + colb;
      char* l = (char*)&sB[buf][0] + rr * 4096 + wave * 1024;
      __builtin_amdgcn_global_load_lds((const __attribute__((address_space(1))) void*)g,
                                       (__attribute__((address_space(3))) void*)l, 16, 0, 0);
    }
  };

  // A staging (x fp32): 64x32 tile; thread t: row t>>2, cols (t&3)*8..+8
  float4 xa[2];
  const int arow = tid >> 2;
  const int ac0  = (tid & 3) * 8;
  auto loadA = [&](int kt) {
    const float* g = x + (long)(bm + arow) * K + kt + ac0;
    xa[0] = *(const float4*)g;
    xa[1] = *(const float4*)(g + 4);
  };
  auto writeA = [&](int buf) {
    *(u16x8*)&sA[buf][arow * BK + ac0] = cvt8(xa[0], xa[1]);
  };

  loadA(0); writeA(0);
  stageB(0, 0);
  __syncthreads();

  const int NT = K / BK;   // 8
  for (int t = 0; t < NT; ++t) {
    const int cur = t & 1, nxt = cur ^ 1;
    const bool pf = (t + 1 < NT);
    if (pf) {
      loadA((t + 1) * BK);
      stageB(nxt, (t + 1) * BK);
    }

    bf16x8 af[2], bfr[4];
    #pragma unroll
    for (int i = 0; i < 2; i++)
      af[i] = *(const bf16x8*)&sA[cur][(wm * 32 + i * 16 + r) * BK + quad * 8];
    #pragma unroll
    for (int j = 0; j < 4; j++)
      bfr[j] = *(const bf16x8*)&sB[cur][(wn * 64 + j * 16 + r) * BK + quad * 8];
    #pragma unroll
    for (int i = 0; i < 2; i++)
      #pragma unroll
      for (int j = 0; j < 4; j++)
        acc[i][j] = __builtin_amdgcn_mfma_f32_16x16x32_bf16(af[i], bfr[j], acc[i][j], 0, 0, 0);

    if (pf) writeA(nxt);          // cvt+ds_write after MFMAs
    __syncthreads();
  }

  // epilogue: C/D layout col=lane&15, row=quad*4+reg
  #pragma unroll
  for (int i = 0; i < 2; i++) {
    #pragma unroll
    for (int j = 0; j < 4; j++) {
      #pragma unroll
      for (int reg = 0; reg < 4; reg++) {
        const int row = bm + wm * 32 + i * 16 + quad * 4 + reg;
        const int col = bn + wn * 64 + j * 16 + r;
        float v = acc[i][j][reg];
        v = v > 0.f ? v : 0.f;     // relu
        const long idx = (long)row * N + col;
        key_f[idx]  = v;
        key_bf[idx] = f2bf_rne(v);
      }
    }
  }
}

// ================= GEMM2: val_b = key_b @ mem_b^T (unchanged R2 structure) ===
#define BM 128
#define BN 128

__global__ __launch_bounds__(256, 3)
void gemm2(const u16* __restrict__ A, const u16* __restrict__ B,
           float* __restrict__ C,
           int M, int N, int K,
           long sA_batch, long sB_batch, long sC_batch)
{
  __shared__ __align__(16) u16 sA[2][BM * BK];   // 2 x 8 KB
  __shared__ __align__(16) u16 sB[2][BN * BK];   // 2 x 8 KB
  const int tid  = threadIdx.x;
  const int wave = tid >> 6;
  const int lane = tid & 63;
  const int quad = lane >> 4;
  const int r    = lane & 15;
  const int wm   = wave >> 1;
  const int wn   = wave & 1;

  // XCD-chunked bijective swizzle: batch b -> XCD b (grid (8,16,8))
  const int gx  = gridDim.x, gy = gridDim.y;
  const int nwg = gx * gy * (int)gridDim.z;
  const int id  = (int)blockIdx.x + gx * ((int)blockIdx.y + gy * (int)blockIdx.z);
  const int cpx = nwg >> 3;
  const int lid = (id & 7) * cpx + (id >> 3);
  const int bx  = lid % gx;
  const int tq  = lid / gx;
  const int by  = tq % gy;
  const int bz  = tq / gy;

  const int bm    = by * BM;
  const int bn    = bx * BN;
  const int batch = bz;

  const char* Ab = (const char*)(A + (long)batch * sA_batch);
  const char* Bb = (const char*)(B + (long)batch * sB_batch);
  const long ldr = (long)K * 2;

  f32x4 acc[4][4];
  #pragma unroll
  for (int i = 0; i < 4; i++)
    #pragma unroll
    for (int j = 0; j < 4; j++)
      acc[i][j] = f32x4{0.f, 0.f, 0.f, 0.f};

  const int o0 = wave * 1024 + lane * 16;
  auto stage = [&](u16* dst, const char* src, int kt) {
    #pragma unroll
    for (int rr = 0; rr < 2; rr++) {
      const int o    = rr * 4096 + o0;
      const int row  = o >> 6;
      const int colb = o & 63;
      const char* g = src + (long)row * ldr + (long)kt * 2 + colb;
      char* l = (char*)dst + rr * 4096 + wave * 1024;
      __builtin_amdgcn_global_load_lds((const __attribute__((address_space(1))) void*)g,
                                       (__attribute__((address_space(3))) void*)l, 16, 0, 0);
    }
  };

  stage(&sA[0][0], Ab + (long)bm * ldr, 0);
  stage(&sB[0][0], Bb + (long)bn * ldr, 0);
  __syncthreads();

  const int NT = K / BK;
  for (int t = 0; t < NT; ++t) {
    const int cur = t & 1, nxt = cur ^ 1;
    const bool pf = (t + 1 < NT);
    if (pf) {
      stage(&sA[nxt][0], Ab + (long)bm * ldr, (t + 1) * BK);
      stage(&sB[nxt][0], Bb + (long)bn * ldr, (t + 1) * BK);
    }

    bf16x8 af[4], bfr[4];
    #pragma unroll
    for (int i = 0; i < 4; i++)
      af[i] = *(const bf16x8*)&sA[cur][(wm * 64 + i * 16 + r) * BK + quad * 8];
    #pragma unroll
    for (int j = 0; j < 4; j++)
      bfr[j] = *(const bf16x8*)&sB[cur][(wn * 64 + j * 16 + r) * BK + quad * 8];
    #pragma unroll
    for (int i = 0; i < 4; i++)
      #pragma unroll
      for (int j = 0; j < 4; j++)
        acc[i][j] = __builtin_amdgcn_mfma_f32_16x16x32_bf16(af[i], bfr[j], acc[i][j], 0, 0, 0);

    __syncthreads();
  }

  float* Co = C + (long)batch * sC_batch;
  #pragma unroll
  for (int i = 0; i < 4; i++) {
    #pragma unroll
    for (int j = 0; j < 4; j++) {
      #pragma unroll
      for (int reg = 0; reg < 4; reg++) {
        const int row = bm + wm * 64 + i * 16 + quad * 4 + reg;
        const int col = bn + wn * 64 + j * 16 + r;
        Co[(long)row * N + col] = acc[i][j][reg];
      }
    }
  }
}

extern "C" void kernel_launch(void* const* d_in, const int* in_sizes, int n_in,
                              void* d_out, int out_size, void* d_ws, size_t ws_size,
                              hipStream_t stream) {
  const float* x   = (const float*)d_in[0];  // (8,2048,256)
  const float* mem = (const float*)d_in[1];  // (8,1024,256)
  const float* W   = (const float*)d_in[2];  // (256,256)
  float* out   = (float*)d_out;
  float* key_f = out;            // (16384,256)
  float* val_f = out + NX;       // (8,2048,1024)
  u16* ws     = (u16*)d_ws;
  u16* W_bf   = ws;
  u16* mem_bf = ws + WS_MEM;
  u16* key_bf = ws + WS_KEY;

  // 0) convert W + mem to bf16
  convert_bf16_kernel<<<(int)((NW + NM) / 8 / 256), 256, 0, stream>>>(mem, W, ws);

  // 1) key = relu(x @ W^T): M=16384, N=256, K=256; BM=64 => 512 blocks (2/CU)
  dim3 g1(256 / G1_BN, 16384 / G1_BM, 1);
  gemm1_x<<<g1, 256, 0, stream>>>(x, W_bf, key_f, key_bf);

  // 2) val_b = key_b @ mem_b^T: per batch M=2048, N=1024, K=256
  dim3 g2(1024 / BN, 2048 / BM, 8);
  gemm2<<<g2, 256, 0, stream>>>(key_bf, mem_bf, val_f,
                                2048, 1024, 256,
                                (long)2048 * 256, (long)1024 * 256,
                                (long)2048 * 1024);
}